// Round 8
// baseline (92.553 us; speedup 1.0000x reference)
//
#include <hip/hip_runtime.h>

#define D     4096
#define NERR  8192
#define DF4   (D / 4)         // 1024 f4 per row
#define NBLK  256
#define SF4   4               // f4-cols per strip (16 cols, 64 B/row segment)
#define TPB   1024
#define RPP   (TPB / SF4)     // 256 rows per pass
#define NPASS (NERR / RPP)    // 32 passes
#define NWAVE (TPB / 64)      // 16

typedef float f32x4 __attribute__((ext_vector_type(4)));

// 256 identical blocks; block owns strip s: cols [16s,16s+16), bottom rows
// [16s,16s+16). phase1 reduce -> finalize -> phase2 scaled-top -> phase3 fill.
__global__ __launch_bounds__(TPB) void k_fused(const f32x4* __restrict__ e4,
                                               const f32x4* __restrict__ c4,
                                               f32x4* __restrict__ oc4,
                                               f32x4* __restrict__ top4,
                                               f32x4* __restrict__ bot4) {
    __shared__ f32x4 wred[NWAVE * SF4];   // 64 entries
    __shared__ f32x4 scl[SF4];

    const int t    = threadIdx.x;
    const int lane = t & 63;
    const int w    = t >> 6;
    const int cf   = t & (SF4 - 1);       // f4-col within strip
    const int r0   = t >> 2;              // row within pass, 0..255
    // XCD-aware strip map: blocks on the same XCD (bid%8 equal) get adjacent
    // strips so shared 128B lines are fetched once per XCD.
    const int s    = (blockIdx.x & 7) * 32 + (blockIdx.x >> 3);
    const int off  = s * SF4 + cf;        // global f4-col

    // ---- phase 1: |e| column sums over the strip (allocate e in cache)
    f32x4 acc = (f32x4)(0.f, 0.f, 0.f, 0.f);
    #pragma unroll 8
    for (int k = 0; k < NPASS; ++k) {
        f32x4 v = e4[(size_t)(k * RPP + r0) * DF4 + off];
        acc.x += fabsf(v.x);
        acc.y += fabsf(v.y);
        acc.z += fabsf(v.z);
        acc.w += fabsf(v.w);
    }
    // wave reduce: lanes with equal (lane&3) share a f4-col; strides 4..32
    #pragma unroll
    for (int st = 4; st <= 32; st <<= 1) {
        acc.x += __shfl_xor(acc.x, st, 64);
        acc.y += __shfl_xor(acc.y, st, 64);
        acc.z += __shfl_xor(acc.z, st, 64);
        acc.w += __shfl_xor(acc.w, st, 64);
    }
    if (lane < SF4) wred[w * SF4 + lane] = acc;
    __syncthreads();

    // ---- finalize: 4 threads, one f4-col (4 columns) each
    if (t < SF4) {
        f32x4 apt = wred[t];
        #pragma unroll
        for (int w2 = 1; w2 < NWAVE; ++w2) apt += wred[w2 * SF4 + t];
        const int g = s * SF4 + t;        // global f4-col
        const f32x4 cen = c4[g];
        f32x4 oc, cs;
        #pragma unroll
        for (int j = 0; j < 4; ++j) {
            const float c  = cen[j];
            const float ub = c + apt[j];
            const float lb = c - apt[j];
            const bool cross = (ub > 0.f) && (lb < 0.f);
            const bool act   = (lb >= 0.f);
            const float denom = cross ? (ub - lb) : 1.f;
            const float slope = cross ? (ub / denom) : 0.f;
            const float mu    = cross ? (-slope * lb * 0.5f) : 0.f;
            oc[j] = act ? c : (slope * c + mu);
            cs[j] = act ? 1.f : slope;
            // diagonal f4 of bottom row (4g+j) sits at f4-col g
            f32x4 dv = (f32x4)(0.f, 0.f, 0.f, 0.f);
            dv[j] = mu;
            __builtin_nontemporal_store(dv, &bot4[(size_t)(4 * g + j) * DF4 + g]);
        }
        oc4[g] = oc;
        scl[t] = cs;
    }
    __syncthreads();

    // ---- phase 2: re-read strip (cache-hit) -> scaled top, NT store
    const f32x4 cs = scl[cf];
    #pragma unroll 8
    for (int k = 0; k < NPASS; ++k) {
        const size_t idx = (size_t)(k * RPP + r0) * DF4 + off;
        f32x4 v = e4[idx];
        v *= cs;
        __builtin_nontemporal_store(v, &top4[idx]);
    }

    // ---- phase 3: zero-fill bottom rows [16s,16s+16), skip the diag f4
    const int r  = 16 * s + (t >> 6);     // one row per wave
    const int c0 = t & 63;
    const int dg = r >> 2;                // diag f4-col of this row
    const f32x4 z = (f32x4)(0.f, 0.f, 0.f, 0.f);
    #pragma unroll
    for (int j = 0; j < 16; ++j) {
        const int c = c0 + j * 64;
        if (c != dg)
            __builtin_nontemporal_store(z, &bot4[(size_t)r * DF4 + c]);
    }
}

extern "C" void kernel_launch(void* const* d_in, const int* in_sizes, int n_in,
                              void* d_out, int out_size, void* d_ws, size_t ws_size,
                              hipStream_t stream) {
    const float* center = (const float*)d_in[0];   // (4096,)
    const float* error  = (const float*)d_in[1];   // (8192, 4096)
    float* out = (float*)d_out;

    float* out_center = out;                                   // (4096,)
    float* out_top    = out + D;                               // (8192, 4096)
    float* out_bottom = out + (size_t)D + (size_t)NERR * D;    // (4096, 4096)

    k_fused<<<NBLK, TPB, 0, stream>>>(
        (const f32x4*)error, (const f32x4*)center,
        (f32x4*)out_center, (f32x4*)out_top, (f32x4*)out_bottom);
}

// Round 9
// 72.010 us; speedup vs baseline: 1.2853x; 1.2853x over previous
//
#include <hip/hip_runtime.h>

#define D      4096
#define NERR   8192
#define DF4    (D / 4)          // 1024 f4 per row
#define NBLK   256
#define NSTRIP 128              // strip = 32 cols = 8 f4 (128 B per row segment)
#define HROWS  (NERR / 2)       // 4096 rows per half
#define TPB    1024
#define RPP    (TPB / 8)        // 128 rows per pass
#define NPASS  (HROWS / RPP)    // 32 passes
#define NWAVE  (TPB / 64)       // 16

typedef float f32x4 __attribute__((ext_vector_type(4)));

// ---------------- k1: partial column sums of |e|, full-line strips -----
// block b: strip s=b>>1 (f4-cols 8s..8s+8), half h=b&1 (rows 4096h..+4096).
// Wave = 8 rows x 8 f4-cols = 8 fully-used 128B lines per load instruction.
__global__ __launch_bounds__(TPB) void k_reduce(const f32x4* __restrict__ e4,
                                                f32x4* __restrict__ part4) {
    __shared__ f32x4 wred[NWAVE * 8];

    const int t    = threadIdx.x;
    const int lane = t & 63;
    const int w    = t >> 6;
    const int cf   = t & 7;             // f4-col within strip
    const int r0   = t >> 3;            // row within pass, 0..127
    const int s    = blockIdx.x >> 1;
    const int h    = blockIdx.x & 1;
    const int off  = s * 8 + cf;
    const size_t rbase = (size_t)h * HROWS;

    f32x4 acc = (f32x4)(0.f, 0.f, 0.f, 0.f);
    #pragma unroll 8
    for (int k = 0; k < NPASS; ++k) {
        f32x4 v = e4[(rbase + k * RPP + r0) * DF4 + off];
        acc.x += fabsf(v.x);
        acc.y += fabsf(v.y);
        acc.z += fabsf(v.z);
        acc.w += fabsf(v.w);
    }
    // butterfly over row bits of lane (bits 3..5); lanes keep per-cf sums
    #pragma unroll
    for (int st = 8; st <= 32; st <<= 1) {
        acc.x += __shfl_xor(acc.x, st, 64);
        acc.y += __shfl_xor(acc.y, st, 64);
        acc.z += __shfl_xor(acc.z, st, 64);
        acc.w += __shfl_xor(acc.w, st, 64);
    }
    if (lane < 8) wred[w * 8 + lane] = acc;
    __syncthreads();

    if (t < 8) {
        f32x4 sum = wred[t];
        #pragma unroll
        for (int w2 = 1; w2 < NWAVE; ++w2) sum += wred[w2 * 8 + t];
        part4[(size_t)(s * 2 + h) * 8 + t] = sum;   // 128 B per block
    }
}

// ---------------- k2: finalize + scaled top + bottom fill --------------
// Same decomposition. Finalize computed redundantly per strip pair (256 B).
// Top re-read is L3-resident. Bottom rows [32s+16h, +16) incl. diag mu.
__global__ __launch_bounds__(TPB) void k_emit(const f32x4* __restrict__ e4,
                                              const f32x4* __restrict__ part4,
                                              const f32x4* __restrict__ c4,
                                              f32x4* __restrict__ oc4,
                                              f32x4* __restrict__ top4,
                                              f32x4* __restrict__ bot4) {
    __shared__ f32x4 scl[8];
    __shared__ f32x4 muL[8];

    const int t    = threadIdx.x;
    const int cf   = t & 7;
    const int r0   = t >> 3;
    const int s    = blockIdx.x >> 1;
    const int h    = blockIdx.x & 1;
    const int off  = s * 8 + cf;
    const size_t rbase = (size_t)h * HROWS;

    // ---- finalize: 8 threads, one f4-col (4 columns) each
    if (t < 8) {
        const int g = s * 8 + t;
        const f32x4 apt = part4[(size_t)(s * 2) * 8 + t]
                        + part4[(size_t)(s * 2 + 1) * 8 + t];
        const f32x4 cen = c4[g];
        f32x4 oc, cs, mu4;
        #pragma unroll
        for (int j = 0; j < 4; ++j) {
            const float c  = cen[j];
            const float ub = c + apt[j];
            const float lb = c - apt[j];
            const bool cross = (ub > 0.f) && (lb < 0.f);
            const bool act   = (lb >= 0.f);
            const float denom = cross ? (ub - lb) : 1.f;
            const float slope = cross ? (ub / denom) : 0.f;
            const float mu    = cross ? (-slope * lb * 0.5f) : 0.f;
            oc[j]  = act ? c : (slope * c + mu);
            cs[j]  = act ? 1.f : slope;
            mu4[j] = mu;
        }
        scl[t] = cs;
        muL[t] = mu4;
        if (h == 0) oc4[g] = oc;
    }
    __syncthreads();

    // ---- top: re-read own half (L3 hit), scale, NT store
    const f32x4 cs = scl[cf];
    #pragma unroll 8
    for (int k = 0; k < NPASS; ++k) {
        const size_t idx = (rbase + k * RPP + r0) * DF4 + off;
        f32x4 v = e4[idx];
        v *= cs;
        __builtin_nontemporal_store(v, &top4[idx]);
    }

    // ---- bottom: rows [32s+16h, +16), one wave per row; diag f4 = mu
    const int w    = t >> 6;
    const int lane = t & 63;
    const int r    = 32 * s + 16 * h + w;
    const int dg   = r >> 2;                    // diag f4-col of row r
    const float muv = muL[(r >> 2) - 8 * s][r & 3];
    #pragma unroll
    for (int j = 0; j < 16; ++j) {
        const int c = lane + j * 64;
        f32x4 v = (f32x4)(0.f, 0.f, 0.f, 0.f);
        if (c == dg) v[r & 3] = muv;
        __builtin_nontemporal_store(v, &bot4[(size_t)r * DF4 + c]);
    }
}

extern "C" void kernel_launch(void* const* d_in, const int* in_sizes, int n_in,
                              void* d_out, int out_size, void* d_ws, size_t ws_size,
                              hipStream_t stream) {
    const float* center = (const float*)d_in[0];   // (4096,)
    const float* error  = (const float*)d_in[1];   // (8192, 4096)
    float* out = (float*)d_out;

    float* out_center = out;                                   // (4096,)
    float* out_top    = out + D;                               // (8192, 4096)
    float* out_bottom = out + (size_t)D + (size_t)NERR * D;    // (4096, 4096)

    f32x4* part4 = (f32x4*)d_ws;   // 256 blocks x 128 B = 32 KB

    k_reduce<<<NBLK, TPB, 0, stream>>>(
        (const f32x4*)error, part4);
    k_emit<<<NBLK, TPB, 0, stream>>>(
        (const f32x4*)error, part4, (const f32x4*)center,
        (f32x4*)out_center, (f32x4*)out_top, (f32x4*)out_bottom);
}